// Round 1
// baseline (188.975 us; speedup 1.0000x reference)
//
#include <hip/hip_runtime.h>
#include <hip/hip_bf16.h>

// Problem constants from the reference.
#define B_SZ   256
#define V_SZ   128000
#define L_KO   32
#define L_EN   32
#define N_NEG  1024
#define EPS_F  1e-8f
#define MARGIN 2.0f
#define NEG_TH 0.1f

// One block per batch row. 256 threads = 4 waves.
//  - wave 0, lanes 0-31 : ko gather -> -log(x+eps)   (masked by ko_len)
//  - wave 0, lanes 32-63: en gather -> -log(x+eps), relu(2-x) (masked by en_len)
//  - all 256 threads    : 4 negative gathers each (1024 total for the row)
// Reduce the 4 partial sums block-wide, then one atomicAdd per output.
__global__ __launch_bounds__(256) void term_loss_kernel(
    const float* __restrict__ rep,
    const int*   __restrict__ ko_ids,
    const int*   __restrict__ ko_len,
    const int*   __restrict__ en_ids,
    const int*   __restrict__ en_len,
    const int*   __restrict__ neg_ids,
    float*       __restrict__ out)
{
    const int b   = blockIdx.x;
    const int tid = threadIdx.x;
    const float* __restrict__ row = rep + (size_t)b * V_SZ;

    float s_self = 0.0f, s_tgt = 0.0f, s_mar = 0.0f, s_neg = 0.0f;

    if (tid < 32) {
        const int l = tid;
        if (l < ko_len[b]) {
            const float v = row[ko_ids[b * L_KO + l]];
            s_self = -logf(v + EPS_F);
        }
    } else if (tid < 64) {
        const int l = tid - 32;
        if (l < en_len[b]) {
            const float v = row[en_ids[b * L_EN + l]];
            s_tgt = -logf(v + EPS_F);
            s_mar = fmaxf(MARGIN - v, 0.0f);
        }
    }

    // Negative-loss gathers: 1024 columns, 4 per thread, coalesced index reads.
    #pragma unroll
    for (int j = tid; j < N_NEG; j += 256) {
        const float v = row[neg_ids[j]];
        s_neg += fmaxf(v - NEG_TH, 0.0f);
    }

    // 64-lane wave reduction.
    #pragma unroll
    for (int off = 32; off > 0; off >>= 1) {
        s_self += __shfl_down(s_self, off, 64);
        s_tgt  += __shfl_down(s_tgt,  off, 64);
        s_mar  += __shfl_down(s_mar,  off, 64);
        s_neg  += __shfl_down(s_neg,  off, 64);
    }

    __shared__ float red[4][4];
    const int wave = tid >> 6;
    if ((tid & 63) == 0) {
        red[wave][0] = s_self;
        red[wave][1] = s_tgt;
        red[wave][2] = s_mar;
        red[wave][3] = s_neg;
    }
    __syncthreads();

    if (tid == 0) {
        float a0 = 0.0f, a1 = 0.0f, a2 = 0.0f, a3 = 0.0f;
        #pragma unroll
        for (int w = 0; w < 4; ++w) {
            a0 += red[w][0];
            a1 += red[w][1];
            a2 += red[w][2];
            a3 += red[w][3];
        }
        const int kl = ko_len[b];
        const int el = en_len[b];
        const float r_self = (kl > 0) ? (a0 / (float)kl) : 0.0f;
        const float r_tgt  = (el > 0) ? (a1 / (float)el) : 0.0f;
        const float r_mar  = (el > 0) ? (a2 / (float)el) : 0.0f;

        atomicAdd(&out[0], r_self * (1.0f / (float)B_SZ));
        atomicAdd(&out[1], r_tgt  * (1.0f / (float)B_SZ));
        atomicAdd(&out[2], r_mar  * (1.0f / (float)B_SZ));
        atomicAdd(&out[3], a3 * (1.0f / ((float)B_SZ * (float)N_NEG)));
    }
}

extern "C" void kernel_launch(void* const* d_in, const int* in_sizes, int n_in,
                              void* d_out, int out_size, void* d_ws, size_t ws_size,
                              hipStream_t stream)
{
    const float* rep     = (const float*)d_in[0];
    const int*   ko_ids  = (const int*)  d_in[1];
    const int*   ko_len  = (const int*)  d_in[2];
    const int*   en_ids  = (const int*)  d_in[3];
    const int*   en_len  = (const int*)  d_in[4];
    const int*   neg_ids = (const int*)  d_in[5];
    float*       out     = (float*)d_out;

    // d_out is re-poisoned to 0xAA before every launch; zero it (capturable).
    hipMemsetAsync(out, 0, 4 * sizeof(float), stream);

    term_loss_kernel<<<B_SZ, 256, 0, stream>>>(
        rep, ko_ids, ko_len, en_ids, en_len, neg_ids, out);
}

// Round 2
// 177.206 us; speedup vs baseline: 1.0664x; 1.0664x over previous
//
#include <hip/hip_runtime.h>
#include <hip/hip_bf16.h>

// Problem constants from the reference.
#define B_SZ   256
#define V_SZ   128000
#define L_KO   32
#define L_EN   32
#define N_NEG  1024
#define EPS_F  1e-8f
#define MARGIN 2.0f
#define NEG_TH 0.1f

// Kernel 1: one block per batch row, 256 threads = 4 waves.
//  - wave 0, lanes 0-31 : ko gather -> -log(x+eps)           (masked by ko_len)
//  - wave 0, lanes 32-63: en gather -> -log(x+eps), relu(2-x) (masked by en_len)
//  - all 256 threads    : 4 negative gathers each (1024 total for the row)
// Writes per-row partials {self_mean, tgt_mean, margin_mean, neg_sum} as
// float4 into d_ws[b]. No atomics, no d_out zeroing needed.
__global__ __launch_bounds__(256) void term_loss_partial(
    const float* __restrict__ rep,
    const int*   __restrict__ ko_ids,
    const int*   __restrict__ ko_len,
    const int*   __restrict__ en_ids,
    const int*   __restrict__ en_len,
    const int*   __restrict__ neg_ids,
    float4*      __restrict__ partials)
{
    const int b   = blockIdx.x;
    const int tid = threadIdx.x;
    const float* __restrict__ row = rep + (size_t)b * V_SZ;

    float s_self = 0.0f, s_tgt = 0.0f, s_mar = 0.0f, s_neg = 0.0f;

    if (tid < 32) {
        if (tid < ko_len[b]) {
            const float v = row[ko_ids[b * L_KO + tid]];
            s_self = -logf(v + EPS_F);
        }
    } else if (tid < 64) {
        const int l = tid - 32;
        if (l < en_len[b]) {
            const float v = row[en_ids[b * L_EN + l]];
            s_tgt = -logf(v + EPS_F);
            s_mar = fmaxf(MARGIN - v, 0.0f);
        }
    }

    // Negative gathers: 4 independent loads per thread (unrolled, one vmcnt batch).
    #pragma unroll
    for (int j = tid; j < N_NEG; j += 256) {
        const float v = row[neg_ids[j]];
        s_neg += fmaxf(v - NEG_TH, 0.0f);
    }

    // 64-lane wave reduction.
    #pragma unroll
    for (int off = 32; off > 0; off >>= 1) {
        s_self += __shfl_down(s_self, off, 64);
        s_tgt  += __shfl_down(s_tgt,  off, 64);
        s_mar  += __shfl_down(s_mar,  off, 64);
        s_neg  += __shfl_down(s_neg,  off, 64);
    }

    __shared__ float red[4][4];
    const int wave = tid >> 6;
    if ((tid & 63) == 0) {
        red[wave][0] = s_self;
        red[wave][1] = s_tgt;
        red[wave][2] = s_mar;
        red[wave][3] = s_neg;
    }
    __syncthreads();

    if (tid == 0) {
        float a0 = 0.0f, a1 = 0.0f, a2 = 0.0f, a3 = 0.0f;
        #pragma unroll
        for (int w = 0; w < 4; ++w) {
            a0 += red[w][0];
            a1 += red[w][1];
            a2 += red[w][2];
            a3 += red[w][3];
        }
        const int kl = ko_len[b];
        const int el = en_len[b];
        float4 p;
        p.x = (kl > 0) ? (a0 / (float)kl) : 0.0f;   // per-row self mean
        p.y = (el > 0) ? (a1 / (float)el) : 0.0f;   // per-row target mean
        p.z = (el > 0) ? (a2 / (float)el) : 0.0f;   // per-row margin mean
        p.w = a3;                                   // per-row negative sum
        partials[b] = p;
    }
}

// Kernel 2: single block, 256 threads. Thread t loads partials[t] (float4),
// block-reduces each component, thread 0 writes the 4 scaled outputs.
__global__ __launch_bounds__(256) void term_loss_reduce(
    const float4* __restrict__ partials,
    float*        __restrict__ out)
{
    const int tid = threadIdx.x;
    float4 p = partials[tid];

    #pragma unroll
    for (int off = 32; off > 0; off >>= 1) {
        p.x += __shfl_down(p.x, off, 64);
        p.y += __shfl_down(p.y, off, 64);
        p.z += __shfl_down(p.z, off, 64);
        p.w += __shfl_down(p.w, off, 64);
    }

    __shared__ float4 red[4];
    const int wave = tid >> 6;
    if ((tid & 63) == 0) red[wave] = p;
    __syncthreads();

    if (tid == 0) {
        float4 a = red[0];
        #pragma unroll
        for (int w = 1; w < 4; ++w) {
            a.x += red[w].x;
            a.y += red[w].y;
            a.z += red[w].z;
            a.w += red[w].w;
        }
        out[0] = a.x * (1.0f / (float)B_SZ);
        out[1] = a.y * (1.0f / (float)B_SZ);
        out[2] = a.z * (1.0f / (float)B_SZ);
        out[3] = a.w * (1.0f / ((float)B_SZ * (float)N_NEG));
    }
}

extern "C" void kernel_launch(void* const* d_in, const int* in_sizes, int n_in,
                              void* d_out, int out_size, void* d_ws, size_t ws_size,
                              hipStream_t stream)
{
    const float* rep     = (const float*)d_in[0];
    const int*   ko_ids  = (const int*)  d_in[1];
    const int*   ko_len  = (const int*)  d_in[2];
    const int*   en_ids  = (const int*)  d_in[3];
    const int*   en_len  = (const int*)  d_in[4];
    const int*   neg_ids = (const int*)  d_in[5];
    float*       out     = (float*)d_out;
    float4*      part    = (float4*)d_ws;   // 256 * 16 B = 4 KB scratch

    term_loss_partial<<<B_SZ, 256, 0, stream>>>(
        rep, ko_ids, ko_len, en_ids, en_len, neg_ids, part);
    term_loss_reduce<<<1, 256, 0, stream>>>(part, out);
}